// Round 7
// baseline (97.098 us; speedup 1.0000x reference)
//
#include <hip/hip_runtime.h>

// ParallelLinear: out[b,t,o] = sum_i x[b,t,i] * W[t,o,i] + bias[t,o]
// B=512, T=1024, ISIZE=OSIZE=64, fp32 in/out.
//
// v7: HBM-granule fix. R0/R2/R6 all pin at ~86us rocprof with every pipe
// idle (Mfma 5.6%, VALU 18%, conflicts 0, BW 39%): one-t-per-block makes
// every global extent a 256B island at 256KB pow-2 stride -> HBM row-
// activation-limited (~half of streaming BW; measured 3.1 of 6.29 TB/s).
// Block now covers 4 CONSECUTIVE t's: x reads and out writes become 1KB
// contiguous per b-row (4x fewer activates per byte).
//
// Structure: 256 thr = 4 waves; wave w owns t = T0+w completely (64 rows x
// 64 o). W[t] lives in the wave's REGISTERS as MFMA B-frags (hi/lo bf16,
// 64 VGPR), gathered from global (L2/L3-hot: each W quad re-read by 8
// chunk-blocks). X staged once as 4 bf16 hi/lo LDS planes (2-way-max
// swizzle, verified per 16-lane phase). Epilogue: accs -> LDS (stride 272,
// conflict-free) -> 1KB-contiguous global flush. Numerics = R6's verified
// 3-term hi/lo split (absmax 0.0156 passed).
// LDS 68KB (planes 64KB, epilogue alias 68KB) -> 2 blocks/CU.

#define T_DIM 1024
#define B_DIM 512
#define KSZ 64
#define OSZ 64
#define ROWS 64
#define NT 4
#define RS 272               // epilogue row stride in f32 (16B-aligned, bank-spread)

typedef __attribute__((ext_vector_type(8))) short   short8;   // 8 bf16
typedef __attribute__((ext_vector_type(4))) float   f32x4;

static __device__ __forceinline__ unsigned short f2bf(float f) {
    unsigned u = __float_as_uint(f);
    u += 0x7FFFu + ((u >> 16) & 1u);          // RNE
    return (unsigned short)(u >> 16);
}
static __device__ __forceinline__ float bf2f(unsigned short h) {
    return __uint_as_float((unsigned)h << 16);
}

__global__ __launch_bounds__(256, 2) void pl_kernel(
    const float* __restrict__ x,
    const float* __restrict__ W,
    const float* __restrict__ bias,
    float* __restrict__ out)
{
    __shared__ __align__(16) unsigned char smem[69632];
    unsigned short* Xh = (unsigned short*)smem;            // [4 planes][64 r][64 k] swizzled
    unsigned short* Xl = (unsigned short*)(smem + 32768);
    float* Ob = (float*)smem;                              // epilogue alias [64][RS]

    const int quad  = blockIdx.x >> 3;     // 0..255  -> t-quad
    const int chunk = blockIdx.x & 7;      // 0..7    -> 64-row band
    const int T0    = quad * NT;
    const int row0  = chunk * ROWS;
    const int tid   = threadIdx.x;
    const int w     = tid >> 6;            // wave id = t-slot
    const int l     = tid & 63;
    const int n     = l & 15;              // o-low / m-row within frag
    const int kq    = l >> 4;              // 0..3 k-quarter

    // ================= W gather: wave w -> registers (B-frags) =================
    // B-frag lane layout (R6-verified): lane holds W[o = 16ct + n][k = (ks*4+kq)*8 + j]
    short8 wh[4][2], wl[4][2];
    {
        const float* wp = W + ((size_t)(T0 + w) * OSZ + n) * KSZ + kq * 8;
        #pragma unroll
        for (int ct = 0; ct < 4; ++ct) {
            #pragma unroll
            for (int ks = 0; ks < 2; ++ks) {
                const float* p = wp + (size_t)ct * 16 * KSZ + ks * 32;
                float4 f0 = *(const float4*)(p);
                float4 f1 = *(const float4*)(p + 4);
                float a[8] = {f0.x, f0.y, f0.z, f0.w, f1.x, f1.y, f1.z, f1.w};
                short8 h, lo;
                #pragma unroll
                for (int j = 0; j < 8; ++j) {
                    unsigned short hh = f2bf(a[j]);
                    h[j]  = (short)hh;
                    lo[j] = (short)f2bf(a[j] - bf2f(hh));
                }
                wh[ct][ks] = h; wl[ct][ks] = lo;
            }
        }
    }

    // ================= X staging: 1KB-contiguous reads, swizzled planes =========
    // thread (sr = tid>>2, sq = tid&3) loads x[row0+sr][T0+sq][0..63] (256B contig)
    {
        const int sr = tid >> 2;
        const int sq = tid & 3;
        const float* xp = x + ((size_t)(row0 + sr) * T_DIM + (T0 + sq)) * KSZ;
        unsigned short* xh = Xh + sq * 4096 + sr * 64;
        unsigned short* xl = Xl + sq * 4096 + sr * 64;
        const int swz = (sr & 7) ^ ((sq & 1) << 2);   // data granule kb stored at kb^swz
        #pragma unroll
        for (int bb = 0; bb < 4; ++bb) {
            float4 f0 = *(const float4*)(xp + bb * 16);
            float4 f1 = *(const float4*)(xp + bb * 16 + 4);
            float4 f2 = *(const float4*)(xp + bb * 16 + 8);
            float4 f3 = *(const float4*)(xp + bb * 16 + 12);
            float a[8]  = {f0.x, f0.y, f0.z, f0.w, f1.x, f1.y, f1.z, f1.w};
            float b2[8] = {f2.x, f2.y, f2.z, f2.w, f3.x, f3.y, f3.z, f3.w};
            short8 h0, l0, h1, l1;
            #pragma unroll
            for (int j = 0; j < 8; ++j) {
                unsigned short hh = f2bf(a[j]);
                h0[j] = (short)hh; l0[j] = (short)f2bf(a[j] - bf2f(hh));
                unsigned short h2 = f2bf(b2[j]);
                h1[j] = (short)h2; l1[j] = (short)f2bf(b2[j] - bf2f(h2));
            }
            const int g0 = (2 * bb)     ^ swz;
            const int g1 = (2 * bb + 1) ^ swz;
            *(short8*)(xh + g0 * 8) = h0;
            *(short8*)(xl + g0 * 8) = l0;
            *(short8*)(xh + g1 * 8) = h1;
            *(short8*)(xl + g1 * 8) = l1;
        }
    }

    __syncthreads();

    // ================= A-frags: wave reads its own plane (q = w) ===============
    short8 ah[4][2], al[4][2];
    #pragma unroll
    for (int m = 0; m < 4; ++m) {
        const int arow = 16 * m + n;
        const unsigned short* ph = Xh + w * 4096 + arow * 64;
        const unsigned short* pl = Xl + w * 4096 + arow * 64;
        const int s2 = (arow & 7) ^ ((w & 1) << 2);
        #pragma unroll
        for (int ks = 0; ks < 2; ++ks) {
            const int g = (ks * 4 + kq) ^ s2;
            ah[m][ks] = *(const short8*)(ph + g * 8);
            al[m][ks] = *(const short8*)(pl + g * 8);
        }
    }

    __syncthreads();   // all plane reads done; smem may be reused as Ob

    // ================= MFMA: 96 per wave (4m x 4ct x 2ks x 3 terms) ============
    f32x4 acc[4][4] = {};
    #pragma unroll
    for (int m = 0; m < 4; ++m) {
        #pragma unroll
        for (int ct = 0; ct < 4; ++ct) {
            #pragma unroll
            for (int ks = 0; ks < 2; ++ks) {
                acc[m][ct] = __builtin_amdgcn_mfma_f32_16x16x32_bf16(ah[m][ks], wh[ct][ks], acc[m][ct], 0, 0, 0);
                acc[m][ct] = __builtin_amdgcn_mfma_f32_16x16x32_bf16(al[m][ks], wh[ct][ks], acc[m][ct], 0, 0, 0);
                acc[m][ct] = __builtin_amdgcn_mfma_f32_16x16x32_bf16(ah[m][ks], wl[ct][ks], acc[m][ct], 0, 0, 0);
            }
        }
    }

    // ================= epilogue: accs -> Ob (conflict-free) -> 1KB flush =======
    float bv[4];
    #pragma unroll
    for (int ct = 0; ct < 4; ++ct)
        bv[ct] = bias[(size_t)(T0 + w) * OSZ + 16 * ct + n];

    // C-frag map (m89-verified): col = n, row = 4*kq + j within the 16x16 tile
    #pragma unroll
    for (int m = 0; m < 4; ++m)
        #pragma unroll
        for (int ct = 0; ct < 4; ++ct)
            #pragma unroll
            for (int j = 0; j < 4; ++j)
                Ob[(size_t)(16 * m + 4 * kq + j) * RS + w * 68 + 16 * ct + n] =
                    acc[m][ct][j] + bv[ct];

    __syncthreads();

    {
        const int sr = tid >> 2;
        const int sq = tid & 3;
        const float* src = Ob + (size_t)sr * RS + sq * 68;
        float* dst = out + ((size_t)(row0 + sr) * T_DIM + (T0 + sq)) * OSZ;
        #pragma unroll
        for (int j = 0; j < 16; ++j)
            *(float4*)(dst + 4 * j) = *(const float4*)(src + 4 * j);
    }
}

extern "C" void kernel_launch(void* const* d_in, const int* in_sizes, int n_in,
                              void* d_out, int out_size, void* d_ws, size_t ws_size,
                              hipStream_t stream) {
    const float* x    = (const float*)d_in[0];
    const float* W    = (const float*)d_in[1];
    const float* bias = (const float*)d_in[2];
    float* out        = (float*)d_out;

    dim3 grid((T_DIM / NT) * (B_DIM / ROWS));   // 256 quads x 8 chunks = 2048 blocks
    dim3 block(256);
    pl_kernel<<<grid, block, 0, stream>>>(x, W, bias, out);
}